// Round 5
// baseline (672.019 us; speedup 1.0000x reference)
//
#include <hip/hip_runtime.h>

// ---------------------------------------------------------------------------
// ZambaSharedBlock: GQA attention block w/ qk-l2norm + FFN + 3 LayerNorms
// B=2 S=2048 DIM=2048 H=16 G=4 DH=128 FF=8192, non-causal, QK_SCALE=10
// Round 5: faithful m201 8-phase GEMM template (2-barrier phases, lead-6
// half-tile staging, one counted vmcnt per K-tile) + split-K=2 for the
// N=2048 GEMMs with LN-fused partial reduction. Attention unchanged.
// ---------------------------------------------------------------------------

typedef __attribute__((ext_vector_type(8))) short short8;
typedef __attribute__((ext_vector_type(4))) float f32x4;
typedef __attribute__((ext_vector_type(16))) float f32x16;

__device__ __forceinline__ unsigned short f2bf(float f) {
  unsigned int u = __builtin_bit_cast(unsigned int, f);
  u += 0x7FFFu + ((u >> 16) & 1u);           // RNE
  return (unsigned short)(u >> 16);
}
__device__ __forceinline__ float bf2f(unsigned short h) {
  unsigned int u = ((unsigned int)h) << 16;
  return __builtin_bit_cast(float, u);
}

typedef const void __attribute__((address_space(1)))* gas1_t;
typedef void __attribute__((address_space(3)))* las3_t;
#define GLDS16(g, l) \
  __builtin_amdgcn_global_load_lds((gas1_t)(const void*)(g), (las3_t)(void*)(l), 16, 0, 0)

// ---------------------------------------------------------------------------
__global__ __launch_bounds__(256) void cast_f32_bf16(const float* __restrict__ src,
                                                     unsigned short* __restrict__ dst,
                                                     int n) {
  int i = (blockIdx.x * 256 + threadIdx.x) * 4;
  if (i >= n) return;
  float4 f = *(const float4*)(src + i);
  uint2 u;
  u.x = (unsigned)f2bf(f.x) | ((unsigned)f2bf(f.y) << 16);
  u.y = (unsigned)f2bf(f.z) | ((unsigned)f2bf(f.w) << 16);
  *(uint2*)(dst + i) = u;
}

// ---------------------------------------------------------------------------
__global__ void transcast(const float* __restrict__ src, unsigned short* __restrict__ dst,
                          int R, int C, int dst_ld, int row_off) {
  __shared__ float t[32][33];
  const int tx = threadIdx.x, ty = threadIdx.y;
  const int c0 = blockIdx.x * 32, r0 = blockIdx.y * 32;
#pragma unroll
  for (int j = 0; j < 4; ++j)
    t[ty + j * 8][tx] = src[(size_t)(r0 + ty + j * 8) * C + c0 + tx];
  __syncthreads();
#pragma unroll
  for (int j = 0; j < 4; ++j)
    dst[(size_t)(row_off + c0 + ty + j * 8) * dst_ld + r0 + tx] = f2bf(t[tx][ty + j * 8]);
}

// ---------------------------------------------------------------------------
// 8-phase GEMM (m201 template): C = A[M][ld] * Bt[N][ld]^T, 256x256 tile,
// BK=64, 8 waves (2Mx4N). Halves {A_k0,B_k0,A_k1,B_k1} of 16KB, dbuf 128KB.
// Phase: {8 ds_read_b128, stage 1 half (2 gload_lds), barrier, lgkmcnt(0),
// sched_barrier, setprio(1), 16 MFMA, setprio(0), [ph3: vmcnt(4)], barrier}.
// Half-tile stream s staged at global phase p = 4T+ph with s = p+6 (lead 6);
// slot-reuse verified: every overwrite >= 2 barriers after slot's last read.
// One vmcnt(4) per K-tile (in-order retire covers all older halves).
// KS>1: blockIdx.z picks a K_eff slice; partial written to C0/C1 (bf16).
template <int KS>
__global__ __launch_bounds__(512, 1) void gemm8ph(const unsigned short* __restrict__ A,
                                                  const unsigned short* __restrict__ Bt,
                                                  unsigned short* __restrict__ C0,
                                                  unsigned short* __restrict__ C1,
                                                  int ldc, int Keff) {
  extern __shared__ char lds[];
  const int tid = threadIdx.x, l = tid & 63, w = tid >> 6;
  const int wr = w >> 2, wc = w & 3;
  // XCD chunked remap within z-slice (nwg % 8 == 0 for all our grids)
  const int gx = gridDim.x, gy = gridDim.y;
  const int did = blockIdx.y * gx + blockIdx.x;
  const int q = (gx * gy) >> 3;
  const int tcm = (did & 7) * q + (did >> 3);
  const int brow = (tcm % gy) * 256, bcol = (tcm / gy) * 256;
  const int ld = Keff * KS;
  const unsigned short* Aa = A + (size_t)brow * ld + blockIdx.z * Keff;
  const unsigned short* Bb = Bt + (size_t)bcol * ld + blockIdx.z * Keff;
  unsigned short* C = (KS == 1 || blockIdx.z == 0) ? C0 : C1;
  const int NT = Keff >> 6;

  // swizzled read offsets (bytes within a 16KB half)
  const int slot = l >> 4;
  const int rowA = wr * 128 + (l & 15);
  const int aRd = ((((rowA << 2) | slot) << 4) ^ ((rowA & 7) << 4));
  const int rowB = wc * 64 + (l & 15);
  const int bRd = ((((rowB << 2) | slot) << 4) ^ ((rowB & 7) << 4));

  f32x4 acc[8][4];
#pragma unroll
  for (int m = 0; m < 8; ++m)
#pragma unroll
    for (int n = 0; n < 4; ++n) acc[m][n] = (f32x4){0.f, 0.f, 0.f, 0.f};

  // stage half-tile s: tile s>>2, kind s&3 (0=A_k0,1=B_k0,2=A_k1,3=B_k1);
  // linear LDS dest, inverse-swizzled global source (rule #21).
  auto stage = [&](int s) {
    const int tile = s >> 2, kind = s & 3;
    const int kofs = ((tile < NT) ? tile * 64 : 0) + (kind >> 1) * 32;
    const unsigned short* src = (kind & 1) ? Bb : Aa;
    char* dst = lds + (tile & 1) * 65536 + kind * 16384;
#pragma unroll
    for (int r = 0; r < 2; ++r) {
      const int g = r * 512 + tid;
      const int rw = ((g >> 3) << 1) | (((g >> 2) ^ (g >> 4)) & 1);
      const int sl = (g ^ rw) & 3;
      GLDS16(src + (size_t)rw * ld + kofs + sl * 8, dst + g * 16);
    }
  };

  // prologue: halves 0..5 (tile0 complete + tile1 A_k0,B_k0); 12 loads.
  stage(0); stage(1); stage(2); stage(3); stage(4); stage(5);
  asm volatile("s_waitcnt vmcnt(4)" ::: "memory");  // tile0 resident
  __builtin_amdgcn_s_barrier();

  for (int T = 0; T < NT; ++T) {
    char* cur = lds + (T & 1) * 65536;
#pragma unroll
    for (int ph = 0; ph < 4; ++ph) {
      const int ks = ph >> 1, mh = ph & 1;
      char* abase = cur + ks * 32768;
      char* bbase = cur + 16384 + ks * 32768;
      short8 af[4], bf[4];
#pragma unroll
      for (int n = 0; n < 4; ++n) bf[n] = *(const short8*)(bbase + bRd + n * 1024);
#pragma unroll
      for (int m = 0; m < 4; ++m) af[m] = *(const short8*)(abase + aRd + (mh * 4 + m) * 1024);
      stage(4 * T + ph + 6);
      __builtin_amdgcn_s_barrier();
      asm volatile("s_waitcnt lgkmcnt(0)" ::: "memory");
      __builtin_amdgcn_sched_barrier(0);
      __builtin_amdgcn_s_setprio(1);
#pragma unroll
      for (int m = 0; m < 4; ++m)
#pragma unroll
        for (int n = 0; n < 4; ++n)
          acc[mh * 4 + m][n] =
              __builtin_amdgcn_mfma_f32_16x16x32_bf16(af[m], bf[n], acc[mh * 4 + m][n], 0, 0, 0);
      __builtin_amdgcn_s_setprio(0);
      if (ph == 3) asm volatile("s_waitcnt vmcnt(4)" ::: "memory");  // tile T+1 resident
      __builtin_amdgcn_s_barrier();
    }
  }

  // epilogue: C/D layout col=lane&15, row=(lane>>4)*4+reg
#pragma unroll
  for (int m = 0; m < 8; ++m)
#pragma unroll
    for (int r = 0; r < 4; ++r) {
      const int row = brow + wr * 128 + m * 16 + (l >> 4) * 4 + r;
#pragma unroll
      for (int n = 0; n < 4; ++n) {
        const int col = bcol + wc * 64 + n * 16 + (l & 15);
        C[(size_t)row * ldc + col] = f2bf(acc[m][n][r]);
      }
    }
}

// ---------------------------------------------------------------------------
__global__ __launch_bounds__(256) void l2norm_qk(unsigned short* __restrict__ qkv) {
  const int wid = blockIdx.x * 4 + (threadIdx.x >> 6);
  const int l = threadIdx.x & 63;
  const int token = wid / 20, u = wid % 20;
  const int col = (u < 16) ? u * 128 : 2048 + (u - 16) * 128;
  unsigned short* p = qkv + (size_t)token * 3072 + col + l * 2;
  const float a = bf2f(p[0]), b = bf2f(p[1]);
  float ss = a * a + b * b;
#pragma unroll
  for (int m = 1; m < 64; m <<= 1) ss += __shfl_xor(ss, m);
  const float sc = ((u < 16) ? 10.f : 1.f) / fmaxf(sqrtf(ss), 1e-12f);
  p[0] = f2bf(a * sc);
  p[1] = f2bf(b * sc);
}

// ---------------------------------------------------------------------------
__global__ __launch_bounds__(256) void vtrans(const unsigned short* __restrict__ qkv,
                                              unsigned short* __restrict__ vt) {
  const int idx = blockIdx.x * 256 + threadIdx.x;
  const int s_ = idx & 2047;
  const int rest = idx >> 11;
  const int d = rest & 127;
  const int bg = rest >> 7;
  const int b = bg >> 2, g = bg & 3;
  vt[idx] = qkv[(size_t)(b * 2048 + s_) * 3072 + 2560 + g * 128 + d];
}

// ---------------------------------------------------------------------------
// Flash attention (round-3 structure, unchanged)
__global__ __launch_bounds__(512) void attn_kernel(const unsigned short* __restrict__ qkv,
                                                   const unsigned short* __restrict__ vt,
                                                   unsigned short* __restrict__ out) {
  extern __shared__ char smem[];
  const int tid = threadIdx.x, w = tid >> 6, l = tid & 63;
  const int hi = l >> 5, l31 = l & 31;

  const int n = blockIdx.x;
  const int np = (n & 7) * 32 + (n >> 3);
  const int qi = np & 7, bh = np >> 3;
  const int b = bh >> 4, h = bh & 15, g = h >> 2;
  const int q0 = qi * 256;

  const unsigned short* kbase = qkv + (size_t)(b * 2048) * 3072 + 2048 + g * 128;
  const unsigned short* vbase = vt + (size_t)(b * 4 + g) * 128 * 2048;

  short8 qf[8];
  {
    const unsigned short* qrow = qkv + (size_t)(b * 2048 + q0 + w * 32 + l31) * 3072 + h * 128;
#pragma unroll
    for (int st = 0; st < 8; ++st)
      qf[st] = *(const short8*)&qrow[st * 16 + hi * 8];
  }

  f32x16 o[4];
#pragma unroll
  for (int d0 = 0; d0 < 4; ++d0)
#pragma unroll
    for (int i = 0; i < 16; ++i) o[d0][i] = 0.f;
  float l_part = 0.f;

  const int krow = tid >> 3, kc = (tid & 7) * 2;
  const int vd = tid >> 2, vc = (tid & 3) * 2;
  const unsigned short* kg = kbase + (size_t)krow * 3072 + kc * 8;
  const unsigned short* vg = vbase + (size_t)vd * 2048 + vc * 8;
  const int ko0 = krow * 256 + ((kc ^ (krow & 15)) << 4);
  const int ko1 = krow * 256 + (((kc + 1) ^ (krow & 15)) << 4);
  const int vrp = vd >> 1, vcl = (vd & 1) * 8;
  const int vo0 = vrp * 256 + (((vcl + vc) ^ (vrp & 15)) << 4);
  const int vo1 = vrp * 256 + (((vcl + vc + 1) ^ (vrp & 15)) << 4);

  {
    uint4 k0 = *(const uint4*)kg, k1 = *(const uint4*)(kg + 8);
    uint4 v0 = *(const uint4*)vg, v1 = *(const uint4*)(vg + 8);
    char* Kb = smem;
    char* Vb = smem + 16384;
    *(uint4*)(Kb + ko0) = k0; *(uint4*)(Kb + ko1) = k1;
    *(uint4*)(Vb + vo0) = v0; *(uint4*)(Vb + vo1) = v1;
  }
  __syncthreads();

  const int swzk = l31 & 15;
  for (int t = 0; t < 32; ++t) {
    uint4 k0, k1, v0, v1;
    const bool more = (t + 1) < 32;
    if (more) {
      const size_t kvo = (size_t)(t + 1) * 64;
      k0 = *(const uint4*)(kg + kvo * 3072);
      k1 = *(const uint4*)(kg + kvo * 3072 + 8);
      v0 = *(const uint4*)(vg + kvo);
      v1 = *(const uint4*)(vg + kvo + 8);
    }

    char* Kb = smem + (t & 1) * 32768;
    char* Vb = Kb + 16384;

    f32x16 s0, s1;
#pragma unroll
    for (int i = 0; i < 16; ++i) { s0[i] = 0.f; s1[i] = 0.f; }
    __builtin_amdgcn_s_setprio(1);
#pragma unroll
    for (int st = 0; st < 8; ++st) {
      const int ch = st * 2 + hi;
      short8 kf0 = *(const short8*)(Kb + l31 * 256 + ((ch ^ swzk) << 4));
      short8 kf1 = *(const short8*)(Kb + (l31 + 32) * 256 + ((ch ^ swzk) << 4));
      s0 = __builtin_amdgcn_mfma_f32_32x32x16_bf16(kf0, qf[st], s0, 0, 0, 0);
      s1 = __builtin_amdgcn_mfma_f32_32x32x16_bf16(kf1, qf[st], s1, 0, 0, 0);
    }
    __builtin_amdgcn_s_setprio(0);

#pragma unroll
    for (int i = 0; i < 16; ++i) {
      s0[i] = __expf(s0[i] - 10.f);
      s1[i] = __expf(s1[i] - 10.f);
      l_part += s0[i] + s1[i];
    }

    short8 pa[4];
#pragma unroll
    for (int ks = 0; ks < 4; ++ks) {
      const f32x16& sv = (ks < 2) ? s0 : s1;
      const int base = (ks & 1) * 8;
      auto pk = [](float x, float y) -> unsigned {
        unsigned ux = __builtin_bit_cast(unsigned, x);
        unsigned uy = __builtin_bit_cast(unsigned, y);
        return ((uy + 0x8000u) & 0xFFFF0000u) | ((ux + 0x8000u) >> 16);
      };
      unsigned a = pk(sv[base + 0], sv[base + 1]);
      unsigned bq = pk(sv[base + 4], sv[base + 5]);
      unsigned c = pk(sv[base + 2], sv[base + 3]);
      unsigned d = pk(sv[base + 6], sv[base + 7]);
      unsigned as = __shfl_xor(a, 32), bs = __shfl_xor(bq, 32);
      unsigned cs = __shfl_xor(c, 32), ds = __shfl_xor(d, 32);
      uint4 wv;
      wv.x = (l < 32) ? a : bs;
      wv.y = (l < 32) ? c : ds;
      wv.z = (l < 32) ? as : bq;
      wv.w = (l < 32) ? cs : d;
      pa[ks] = __builtin_bit_cast(short8, wv);
    }

    __builtin_amdgcn_s_setprio(1);
#pragma unroll
    for (int ks = 0; ks < 4; ++ks) {
#pragma unroll
      for (int d0 = 0; d0 < 4; ++d0) {
        const int dd = d0 * 32 + l31;
        const int rp = dd >> 1;
        const int cl = ((dd & 1) * 8 + ks * 2 + hi) ^ (rp & 15);
        short8 vf = *(const short8*)(Vb + rp * 256 + (cl << 4));
        o[d0] = __builtin_amdgcn_mfma_f32_32x32x16_bf16(pa[ks], vf, o[d0], 0, 0, 0);
      }
    }
    __builtin_amdgcn_s_setprio(0);

    __syncthreads();
    if (more) {
      char* Kn = smem + ((t + 1) & 1) * 32768;
      char* Vn = Kn + 16384;
      *(uint4*)(Kn + ko0) = k0; *(uint4*)(Kn + ko1) = k1;
      *(uint4*)(Vn + vo0) = v0; *(uint4*)(Vn + vo1) = v1;
    }
    __syncthreads();
  }

  float ltot = l_part + __shfl_xor(l_part, 32);
  float linv = 1.f / ltot;
  const int tok_base = b * 2048 + q0 + w * 32;
#pragma unroll
  for (int r = 0; r < 16; ++r) {
    const int qr = (r & 3) + 8 * (r >> 2) + 4 * hi;
    const float li = __shfl(linv, qr);
    unsigned short* orow = out + (size_t)(tok_base + qr) * 2048 + h * 128 + l31;
#pragma unroll
    for (int d0 = 0; d0 < 4; ++d0)
      orow[d0 * 32] = f2bf(o[d0][r] * li);
  }
}

// ---------------------------------------------------------------------------
// Row LayerNorm: optional split-K partial-sum (SUM2), bias, SiLU, then LN.
template <int NC, bool BIAS, bool SILU, bool OUTF32, bool SUM2>
__global__ __launch_bounds__(256) void ln_row(const unsigned short* __restrict__ src,
                                              const unsigned short* __restrict__ src2,
                                              unsigned short* __restrict__ dstb,
                                              float* __restrict__ dstf,
                                              const float* __restrict__ gamma,
                                              const float* __restrict__ beta,
                                              const float* __restrict__ bias) {
  constexpr int E = NC / 256;
  const int row = blockIdx.x, tid = threadIdx.x;
  const size_t base = (size_t)row * NC + tid * E;
  float v[E];
#pragma unroll
  for (int c = 0; c < E / 8; ++c) {
    uint4 u = *(const uint4*)(src + base + c * 8);
    const unsigned short* us = (const unsigned short*)&u;
#pragma unroll
    for (int j = 0; j < 8; ++j) v[c * 8 + j] = bf2f(us[j]);
  }
  if constexpr (SUM2) {
#pragma unroll
    for (int c = 0; c < E / 8; ++c) {
      uint4 u = *(const uint4*)(src2 + base + c * 8);
      const unsigned short* us = (const unsigned short*)&u;
#pragma unroll
      for (int j = 0; j < 8; ++j) v[c * 8 + j] += bf2f(us[j]);
    }
  }
  if constexpr (BIAS) {
#pragma unroll
    for (int i = 0; i < E; ++i) v[i] += bias[tid * E + i];
  }
  if constexpr (SILU) {
#pragma unroll
    for (int i = 0; i < E; ++i) v[i] = v[i] / (1.f + __expf(-v[i]));
  }
  float s = 0.f, q = 0.f;
#pragma unroll
  for (int i = 0; i < E; ++i) {
    s += v[i];
    q += v[i] * v[i];
  }
#pragma unroll
  for (int m = 1; m < 64; m <<= 1) {
    s += __shfl_xor(s, m);
    q += __shfl_xor(q, m);
  }
  __shared__ float rs[4], rq[4];
  if ((tid & 63) == 0) {
    rs[tid >> 6] = s;
    rq[tid >> 6] = q;
  }
  __syncthreads();
  s = rs[0] + rs[1] + rs[2] + rs[3];
  q = rq[0] + rq[1] + rq[2] + rq[3];
  const float mean = s / NC;
  const float rstd = rsqrtf(q / NC - mean * mean + 1e-5f);
#pragma unroll
  for (int i = 0; i < E; ++i)
    v[i] = (v[i] - mean) * rstd * gamma[tid * E + i] + beta[tid * E + i];
  if constexpr (OUTF32) {
#pragma unroll
    for (int c = 0; c < E / 4; ++c) {
      float4 f = {v[c * 4], v[c * 4 + 1], v[c * 4 + 2], v[c * 4 + 3]};
      *(float4*)(dstf + base + c * 4) = f;
    }
  } else {
#pragma unroll
    for (int c = 0; c < E / 8; ++c) {
      uint4 u;
      unsigned* up = (unsigned*)&u;
#pragma unroll
      for (int j = 0; j < 4; ++j)
        up[j] = (unsigned)f2bf(v[c * 8 + j * 2]) | ((unsigned)f2bf(v[c * 8 + j * 2 + 1]) << 16);
      *(uint4*)(dstb + base + c * 8) = u;
    }
  }
}

// ---------------------------------------------------------------------------
extern "C" void kernel_launch(void* const* d_in, const int* in_sizes, int n_in,
                              void* d_out, int out_size, void* d_ws, size_t ws_size,
                              hipStream_t stream) {
  (void)in_sizes; (void)n_in; (void)out_size; (void)ws_size;
  const float* x     = (const float*)d_in[0];
  const float* wq    = (const float*)d_in[1];
  const float* wk    = (const float*)d_in[2];
  const float* wv    = (const float*)d_in[3];
  const float* wo    = (const float*)d_in[4];
  const float* ln1_g = (const float*)d_in[5];
  const float* ln1_b = (const float*)d_in[6];
  const float* w1    = (const float*)d_in[7];
  const float* b1    = (const float*)d_in[8];
  const float* lnf_g = (const float*)d_in[9];
  const float* lnf_b = (const float*)d_in[10];
  const float* w2    = (const float*)d_in[11];
  const float* b2    = (const float*)d_in[12];

  unsigned short* ws = (unsigned short*)d_ws;
  unsigned short* wqkvT  = ws;                                  // [3072][2048]
  unsigned short* woT    = wqkvT  + (size_t)3072 * 2048;        // [2048][2048]
  unsigned short* w1T    = woT    + (size_t)2048 * 2048;        // [8192][2048]
  unsigned short* w2T    = w1T    + (size_t)8192 * 2048;        // [2048][8192]
  unsigned short* xb     = w2T    + (size_t)2048 * 8192;        // x bf16 -> h -> FFN2 partial0
  unsigned short* qkv    = xb     + (size_t)4096 * 2048;        // qkv -> O-proj partial0
  unsigned short* vt     = qkv    + (size_t)4096 * 3072;        // [8][128][2048]
  unsigned short* attn_o = vt     + (size_t)4096 * 512;         // attn out -> FFN2 partial1
  unsigned short* f1     = attn_o + (size_t)4096 * 2048;        // O-proj partial1 -> FFN1 out

  (void)hipFuncSetAttribute((const void*)gemm8ph<1>,
                            hipFuncAttributeMaxDynamicSharedMemorySize, 131072);
  (void)hipFuncSetAttribute((const void*)gemm8ph<2>,
                            hipFuncAttributeMaxDynamicSharedMemorySize, 131072);
  (void)hipFuncSetAttribute((const void*)attn_kernel,
                            hipFuncAttributeMaxDynamicSharedMemorySize, 65536);

  const dim3 tb(32, 8);
  cast_f32_bf16<<<8192, 256, 0, stream>>>(x, xb, 4096 * 2048);
  transcast<<<dim3(64, 64),  tb, 0, stream>>>(wq, wqkvT, 2048, 2048, 2048, 0);
  transcast<<<dim3(16, 64),  tb, 0, stream>>>(wk, wqkvT, 2048, 512, 2048, 2048);
  transcast<<<dim3(16, 64),  tb, 0, stream>>>(wv, wqkvT, 2048, 512, 2048, 2560);
  transcast<<<dim3(64, 64),  tb, 0, stream>>>(wo, woT, 2048, 2048, 2048, 0);
  transcast<<<dim3(256, 64), tb, 0, stream>>>(w1, w1T, 2048, 8192, 2048, 0);
  transcast<<<dim3(64, 256), tb, 0, stream>>>(w2, w2T, 8192, 2048, 8192, 0);

  // QKV: M=4096 N=3072 K=2048 (KS=1)
  gemm8ph<1><<<dim3(12, 16, 1), 512, 131072, stream>>>(xb, wqkvT, qkv, nullptr, 3072, 2048);
  l2norm_qk<<<20480, 256, 0, stream>>>(qkv);
  vtrans<<<8192, 256, 0, stream>>>(qkv, vt);
  attn_kernel<<<256, 512, 65536, stream>>>(qkv, vt, attn_o);
  // O-proj: M=4096 N=2048 K=2048, split-K=2 -> partials in qkv-region & f1-region
  gemm8ph<2><<<dim3(8, 16, 2), 512, 131072, stream>>>(attn_o, woT, qkv, f1, 2048, 1024);
  ln_row<2048, false, false, false, true><<<4096, 256, 0, stream>>>(
      qkv, f1, xb, nullptr, ln1_g, ln1_b, nullptr);
  // FFN1: M=4096 N=8192 K=2048 (KS=1)
  gemm8ph<1><<<dim3(32, 16, 1), 512, 131072, stream>>>(xb, w1T, f1, nullptr, 8192, 2048);
  ln_row<8192, true, true, false, false><<<4096, 256, 0, stream>>>(
      f1, nullptr, f1, nullptr, lnf_g, lnf_b, b1);
  // FFN2: M=4096 N=2048 K=8192, split-K=2 -> partials in xb-region & attn_o-region
  gemm8ph<2><<<dim3(8, 16, 2), 512, 131072, stream>>>(f1, w2T, xb, attn_o, 2048, 4096);
  ln_row<2048, true, false, true, true><<<4096, 256, 0, stream>>>(
      xb, attn_o, nullptr, (float*)d_out, ln1_g, ln1_b, b2);
}

// Round 6
// 645.167 us; speedup vs baseline: 1.0416x; 1.0416x over previous
//
#include <hip/hip_runtime.h>

// ---------------------------------------------------------------------------
// ZambaSharedBlock: GQA attention block w/ qk-l2norm + FFN + 3 LayerNorms
// B=2 S=2048 DIM=2048 H=16 G=4 DH=128 FF=8192, non-causal, QK_SCALE=10
// Round 6: GEMM with cross-phase pipelined ds_reads (next phase's fragments
// issued before this phase's MFMA cluster -> only one blocking LDS drain per
// K-tile) + B-frag reuse (24 instead of 32 b128 per wave per K-tile).
// Attention / LN / prep / launch structure unchanged from round 5.
// ---------------------------------------------------------------------------

typedef __attribute__((ext_vector_type(8))) short short8;
typedef __attribute__((ext_vector_type(4))) float f32x4;
typedef __attribute__((ext_vector_type(16))) float f32x16;

__device__ __forceinline__ unsigned short f2bf(float f) {
  unsigned int u = __builtin_bit_cast(unsigned int, f);
  u += 0x7FFFu + ((u >> 16) & 1u);           // RNE
  return (unsigned short)(u >> 16);
}
__device__ __forceinline__ float bf2f(unsigned short h) {
  unsigned int u = ((unsigned int)h) << 16;
  return __builtin_bit_cast(float, u);
}

typedef const void __attribute__((address_space(1)))* gas1_t;
typedef void __attribute__((address_space(3)))* las3_t;
#define GLDS16(g, l) \
  __builtin_amdgcn_global_load_lds((gas1_t)(const void*)(g), (las3_t)(void*)(l), 16, 0, 0)

// ---------------------------------------------------------------------------
__global__ __launch_bounds__(256) void cast_f32_bf16(const float* __restrict__ src,
                                                     unsigned short* __restrict__ dst,
                                                     int n) {
  int i = (blockIdx.x * 256 + threadIdx.x) * 4;
  if (i >= n) return;
  float4 f = *(const float4*)(src + i);
  uint2 u;
  u.x = (unsigned)f2bf(f.x) | ((unsigned)f2bf(f.y) << 16);
  u.y = (unsigned)f2bf(f.z) | ((unsigned)f2bf(f.w) << 16);
  *(uint2*)(dst + i) = u;
}

// ---------------------------------------------------------------------------
__global__ void transcast(const float* __restrict__ src, unsigned short* __restrict__ dst,
                          int R, int C, int dst_ld, int row_off) {
  __shared__ float t[32][33];
  const int tx = threadIdx.x, ty = threadIdx.y;
  const int c0 = blockIdx.x * 32, r0 = blockIdx.y * 32;
#pragma unroll
  for (int j = 0; j < 4; ++j)
    t[ty + j * 8][tx] = src[(size_t)(r0 + ty + j * 8) * C + c0 + tx];
  __syncthreads();
#pragma unroll
  for (int j = 0; j < 4; ++j)
    dst[(size_t)(row_off + c0 + ty + j * 8) * dst_ld + r0 + tx] = f2bf(t[tx][ty + j * 8]);
}

// ---------------------------------------------------------------------------
// 8-phase GEMM with cross-phase read pipelining. C = A[M][ld]*Bt[N][ld]^T,
// 256x256 tile, BK=64, 8 waves (2Mx4N). Halves {A_k0,B_k0,A_k1,B_k1} 16KB,
// dbuf 128KB. Phase p: {stage 1 half, barrier, lgkmcnt(0), issue phase-(p+1)
// ds_reads (pinned by sched_barrier), setprio(1), 16 MFMA, setprio(0),
// [ph3: vmcnt(4)], barrier}. Only ph0 has a blocking read-drain (cross-tile
// reads must follow the vmcnt->barrier pair: other waves' DMA completion is
// only guaranteed there). bf read once per ks, reused over both m-halves.
template <int KS>
__global__ __launch_bounds__(512, 1) void gemm8ph(const unsigned short* __restrict__ A,
                                                  const unsigned short* __restrict__ Bt,
                                                  unsigned short* __restrict__ C0,
                                                  unsigned short* __restrict__ C1,
                                                  int ldc, int Keff) {
  extern __shared__ char lds[];
  const int tid = threadIdx.x, l = tid & 63, w = tid >> 6;
  const int wr = w >> 2, wc = w & 3;
  const int gx = gridDim.x, gy = gridDim.y;
  const int did = blockIdx.y * gx + blockIdx.x;
  const int q = (gx * gy) >> 3;
  const int tcm = (did & 7) * q + (did >> 3);
  const int brow = (tcm % gy) * 256, bcol = (tcm / gy) * 256;
  const int ld = Keff * KS;
  const unsigned short* Aa = A + (size_t)brow * ld + blockIdx.z * Keff;
  const unsigned short* Bb = Bt + (size_t)bcol * ld + blockIdx.z * Keff;
  unsigned short* C = (KS == 1 || blockIdx.z == 0) ? C0 : C1;
  const int NT = Keff >> 6;

  const int slot = l >> 4;
  const int rowA = wr * 128 + (l & 15);
  const int aRd = ((((rowA << 2) | slot) << 4) ^ ((rowA & 7) << 4));
  const int rowB = wc * 64 + (l & 15);
  const int bRd = ((((rowB << 2) | slot) << 4) ^ ((rowB & 7) << 4));

  f32x4 acc[8][4];
#pragma unroll
  for (int m = 0; m < 8; ++m)
#pragma unroll
    for (int n = 0; n < 4; ++n) acc[m][n] = (f32x4){0.f, 0.f, 0.f, 0.f};

  auto stage = [&](int s) {
    const int tile = s >> 2, kind = s & 3;
    const int kofs = ((tile < NT) ? tile * 64 : 0) + (kind >> 1) * 32;
    const unsigned short* src = (kind & 1) ? Bb : Aa;
    char* dst = lds + (tile & 1) * 65536 + kind * 16384;
#pragma unroll
    for (int r = 0; r < 2; ++r) {
      const int g = r * 512 + tid;
      const int rw = ((g >> 3) << 1) | (((g >> 2) ^ (g >> 4)) & 1);
      const int sl = (g ^ rw) & 3;
      GLDS16(src + (size_t)rw * ld + kofs + sl * 8, dst + g * 16);
    }
  };

#define BAR() __builtin_amdgcn_s_barrier()
#define LGKM0() do { asm volatile("s_waitcnt lgkmcnt(0)" ::: "memory"); \
                     __builtin_amdgcn_sched_barrier(0); } while (0)
#define SBAR() __builtin_amdgcn_sched_barrier(0)
#define MFMA16(AF, BF, MO)                                                     \
  do {                                                                         \
    __builtin_amdgcn_s_setprio(1);                                             \
    _Pragma("unroll") for (int m_ = 0; m_ < 4; ++m_)                           \
        _Pragma("unroll") for (int n_ = 0; n_ < 4; ++n_)                       \
            acc[(MO) + m_][n_] = __builtin_amdgcn_mfma_f32_16x16x32_bf16(      \
                (AF)[m_], (BF)[n_], acc[(MO) + m_][n_], 0, 0, 0);              \
    __builtin_amdgcn_s_setprio(0);                                             \
  } while (0)

  // prologue: halves 0..5 (tile0 complete + tile1 A_k0,B_k0)
  stage(0); stage(1); stage(2); stage(3); stage(4); stage(5);
  asm volatile("s_waitcnt vmcnt(4)" ::: "memory");  // own tile0 loads done
  BAR();                                            // => all waves' done

  for (int T = 0; T < NT; ++T) {
    char* cur = lds + (T & 1) * 65536;
    char* A0 = cur, *B0 = cur + 16384, *A1 = cur + 32768, *B1 = cur + 49152;
    short8 af0[4], af1[4], af2[4], af3[4], bf0[4], bf1[4];

    // ---- ph0 (ks0, m0-3): blocking reads for this phase
#pragma unroll
    for (int n = 0; n < 4; ++n) bf0[n] = *(const short8*)(B0 + bRd + n * 1024);
#pragma unroll
    for (int m = 0; m < 4; ++m) af0[m] = *(const short8*)(A0 + aRd + m * 1024);
    stage(4 * T + 6);
    BAR();
    LGKM0();
#pragma unroll
    for (int m = 0; m < 4; ++m) af1[m] = *(const short8*)(A0 + aRd + (4 + m) * 1024);
    SBAR();  // pin ph1 reads above the MFMA cluster
    MFMA16(af0, bf0, 0);
    BAR();

    // ---- ph1 (ks0, m4-7)
    stage(4 * T + 7);
    BAR();
    LGKM0();  // af1 drained under ph0 MFMA
#pragma unroll
    for (int n = 0; n < 4; ++n) bf1[n] = *(const short8*)(B1 + bRd + n * 1024);
#pragma unroll
    for (int m = 0; m < 4; ++m) af2[m] = *(const short8*)(A1 + aRd + m * 1024);
    SBAR();
    MFMA16(af1, bf0, 4);
    BAR();

    // ---- ph2 (ks1, m0-3)
    stage(4 * T + 8);
    BAR();
    LGKM0();  // bf1/af2 drained under ph1 MFMA
#pragma unroll
    for (int m = 0; m < 4; ++m) af3[m] = *(const short8*)(A1 + aRd + (4 + m) * 1024);
    SBAR();
    MFMA16(af2, bf1, 0);
    BAR();

    // ---- ph3 (ks1, m4-7)
    stage(4 * T + 9);
    BAR();
    LGKM0();  // af3 drained under ph2 MFMA
    SBAR();
    MFMA16(af3, bf1, 4);
    asm volatile("s_waitcnt vmcnt(4)" ::: "memory");  // tile T+1 halves done
    BAR();
  }
#undef BAR
#undef LGKM0
#undef SBAR
#undef MFMA16

  // epilogue: C/D layout col=lane&15, row=(lane>>4)*4+reg
#pragma unroll
  for (int m = 0; m < 8; ++m)
#pragma unroll
    for (int r = 0; r < 4; ++r) {
      const int row = brow + wr * 128 + m * 16 + (l >> 4) * 4 + r;
#pragma unroll
      for (int n = 0; n < 4; ++n) {
        const int col = bcol + wc * 64 + n * 16 + (l & 15);
        C[(size_t)row * ldc + col] = f2bf(acc[m][n][r]);
      }
    }
}

// ---------------------------------------------------------------------------
__global__ __launch_bounds__(256) void l2norm_qk(unsigned short* __restrict__ qkv) {
  const int wid = blockIdx.x * 4 + (threadIdx.x >> 6);
  const int l = threadIdx.x & 63;
  const int token = wid / 20, u = wid % 20;
  const int col = (u < 16) ? u * 128 : 2048 + (u - 16) * 128;
  unsigned short* p = qkv + (size_t)token * 3072 + col + l * 2;
  const float a = bf2f(p[0]), b = bf2f(p[1]);
  float ss = a * a + b * b;
#pragma unroll
  for (int m = 1; m < 64; m <<= 1) ss += __shfl_xor(ss, m);
  const float sc = ((u < 16) ? 10.f : 1.f) / fmaxf(sqrtf(ss), 1e-12f);
  p[0] = f2bf(a * sc);
  p[1] = f2bf(b * sc);
}

// ---------------------------------------------------------------------------
__global__ __launch_bounds__(256) void vtrans(const unsigned short* __restrict__ qkv,
                                              unsigned short* __restrict__ vt) {
  const int idx = blockIdx.x * 256 + threadIdx.x;
  const int s_ = idx & 2047;
  const int rest = idx >> 11;
  const int d = rest & 127;
  const int bg = rest >> 7;
  const int b = bg >> 2, g = bg & 3;
  vt[idx] = qkv[(size_t)(b * 2048 + s_) * 3072 + 2560 + g * 128 + d];
}

// ---------------------------------------------------------------------------
// Flash attention (round-3 structure, unchanged)
__global__ __launch_bounds__(512) void attn_kernel(const unsigned short* __restrict__ qkv,
                                                   const unsigned short* __restrict__ vt,
                                                   unsigned short* __restrict__ out) {
  extern __shared__ char smem[];
  const int tid = threadIdx.x, w = tid >> 6, l = tid & 63;
  const int hi = l >> 5, l31 = l & 31;

  const int n = blockIdx.x;
  const int np = (n & 7) * 32 + (n >> 3);
  const int qi = np & 7, bh = np >> 3;
  const int b = bh >> 4, h = bh & 15, g = h >> 2;
  const int q0 = qi * 256;

  const unsigned short* kbase = qkv + (size_t)(b * 2048) * 3072 + 2048 + g * 128;
  const unsigned short* vbase = vt + (size_t)(b * 4 + g) * 128 * 2048;

  short8 qf[8];
  {
    const unsigned short* qrow = qkv + (size_t)(b * 2048 + q0 + w * 32 + l31) * 3072 + h * 128;
#pragma unroll
    for (int st = 0; st < 8; ++st)
      qf[st] = *(const short8*)&qrow[st * 16 + hi * 8];
  }

  f32x16 o[4];
#pragma unroll
  for (int d0 = 0; d0 < 4; ++d0)
#pragma unroll
    for (int i = 0; i < 16; ++i) o[d0][i] = 0.f;
  float l_part = 0.f;

  const int krow = tid >> 3, kc = (tid & 7) * 2;
  const int vd = tid >> 2, vc = (tid & 3) * 2;
  const unsigned short* kg = kbase + (size_t)krow * 3072 + kc * 8;
  const unsigned short* vg = vbase + (size_t)vd * 2048 + vc * 8;
  const int ko0 = krow * 256 + ((kc ^ (krow & 15)) << 4);
  const int ko1 = krow * 256 + (((kc + 1) ^ (krow & 15)) << 4);
  const int vrp = vd >> 1, vcl = (vd & 1) * 8;
  const int vo0 = vrp * 256 + (((vcl + vc) ^ (vrp & 15)) << 4);
  const int vo1 = vrp * 256 + (((vcl + vc + 1) ^ (vrp & 15)) << 4);

  {
    uint4 k0 = *(const uint4*)kg, k1 = *(const uint4*)(kg + 8);
    uint4 v0 = *(const uint4*)vg, v1 = *(const uint4*)(vg + 8);
    char* Kb = smem;
    char* Vb = smem + 16384;
    *(uint4*)(Kb + ko0) = k0; *(uint4*)(Kb + ko1) = k1;
    *(uint4*)(Vb + vo0) = v0; *(uint4*)(Vb + vo1) = v1;
  }
  __syncthreads();

  const int swzk = l31 & 15;
  for (int t = 0; t < 32; ++t) {
    uint4 k0, k1, v0, v1;
    const bool more = (t + 1) < 32;
    if (more) {
      const size_t kvo = (size_t)(t + 1) * 64;
      k0 = *(const uint4*)(kg + kvo * 3072);
      k1 = *(const uint4*)(kg + kvo * 3072 + 8);
      v0 = *(const uint4*)(vg + kvo);
      v1 = *(const uint4*)(vg + kvo + 8);
    }

    char* Kb = smem + (t & 1) * 32768;
    char* Vb = Kb + 16384;

    f32x16 s0, s1;
#pragma unroll
    for (int i = 0; i < 16; ++i) { s0[i] = 0.f; s1[i] = 0.f; }
    __builtin_amdgcn_s_setprio(1);
#pragma unroll
    for (int st = 0; st < 8; ++st) {
      const int ch = st * 2 + hi;
      short8 kf0 = *(const short8*)(Kb + l31 * 256 + ((ch ^ swzk) << 4));
      short8 kf1 = *(const short8*)(Kb + (l31 + 32) * 256 + ((ch ^ swzk) << 4));
      s0 = __builtin_amdgcn_mfma_f32_32x32x16_bf16(kf0, qf[st], s0, 0, 0, 0);
      s1 = __builtin_amdgcn_mfma_f32_32x32x16_bf16(kf1, qf[st], s1, 0, 0, 0);
    }
    __builtin_amdgcn_s_setprio(0);

#pragma unroll
    for (int i = 0; i < 16; ++i) {
      s0[i] = __expf(s0[i] - 10.f);
      s1[i] = __expf(s1[i] - 10.f);
      l_part += s0[i] + s1[i];
    }

    short8 pa[4];
#pragma unroll
    for (int ks = 0; ks < 4; ++ks) {
      const f32x16& sv = (ks < 2) ? s0 : s1;
      const int base = (ks & 1) * 8;
      auto pk = [](float x, float y) -> unsigned {
        unsigned ux = __builtin_bit_cast(unsigned, x);
        unsigned uy = __builtin_bit_cast(unsigned, y);
        return ((uy + 0x8000u) & 0xFFFF0000u) | ((ux + 0x8000u) >> 16);
      };
      unsigned a = pk(sv[base + 0], sv[base + 1]);
      unsigned bq = pk(sv[base + 4], sv[base + 5]);
      unsigned c = pk(sv[base + 2], sv[base + 3]);
      unsigned d = pk(sv[base + 6], sv[base + 7]);
      unsigned as = __shfl_xor(a, 32), bs = __shfl_xor(bq, 32);
      unsigned cs = __shfl_xor(c, 32), ds = __shfl_xor(d, 32);
      uint4 wv;
      wv.x = (l < 32) ? a : bs;
      wv.y = (l < 32) ? c : ds;
      wv.z = (l < 32) ? as : bq;
      wv.w = (l < 32) ? cs : d;
      pa[ks] = __builtin_bit_cast(short8, wv);
    }

    __builtin_amdgcn_s_setprio(1);
#pragma unroll
    for (int ks = 0; ks < 4; ++ks) {
#pragma unroll
      for (int d0 = 0; d0 < 4; ++d0) {
        const int dd = d0 * 32 + l31;
        const int rp = dd >> 1;
        const int cl = ((dd & 1) * 8 + ks * 2 + hi) ^ (rp & 15);
        short8 vf = *(const short8*)(Vb + rp * 256 + (cl << 4));
        o[d0] = __builtin_amdgcn_mfma_f32_32x32x16_bf16(pa[ks], vf, o[d0], 0, 0, 0);
      }
    }
    __builtin_amdgcn_s_setprio(0);

    __syncthreads();
    if (more) {
      char* Kn = smem + ((t + 1) & 1) * 32768;
      char* Vn = Kn + 16384;
      *(uint4*)(Kn + ko0) = k0; *(uint4*)(Kn + ko1) = k1;
      *(uint4*)(Vn + vo0) = v0; *(uint4*)(Vn + vo1) = v1;
    }
    __syncthreads();
  }

  float ltot = l_part + __shfl_xor(l_part, 32);
  float linv = 1.f / ltot;
  const int tok_base = b * 2048 + q0 + w * 32;
#pragma unroll
  for (int r = 0; r < 16; ++r) {
    const int qr = (r & 3) + 8 * (r >> 2) + 4 * hi;
    const float li = __shfl(linv, qr);
    unsigned short* orow = out + (size_t)(tok_base + qr) * 2048 + h * 128 + l31;
#pragma unroll
    for (int d0 = 0; d0 < 4; ++d0)
      orow[d0 * 32] = f2bf(o[d0][r] * li);
  }
}

// ---------------------------------------------------------------------------
// Row LayerNorm: optional split-K partial-sum (SUM2), bias, SiLU, then LN.
template <int NC, bool BIAS, bool SILU, bool OUTF32, bool SUM2>
__global__ __launch_bounds__(256) void ln_row(const unsigned short* __restrict__ src,
                                              const unsigned short* __restrict__ src2,
                                              unsigned short* __restrict__ dstb,
                                              float* __restrict__ dstf,
                                              const float* __restrict__ gamma,
                                              const float* __restrict__ beta,
                                              const float* __restrict__ bias) {
  constexpr int E = NC / 256;
  const int row = blockIdx.x, tid = threadIdx.x;
  const size_t base = (size_t)row * NC + tid * E;
  float v[E];
#pragma unroll
  for (int c = 0; c < E / 8; ++c) {
    uint4 u = *(const uint4*)(src + base + c * 8);
    const unsigned short* us = (const unsigned short*)&u;
#pragma unroll
    for (int j = 0; j < 8; ++j) v[c * 8 + j] = bf2f(us[j]);
  }
  if constexpr (SUM2) {
#pragma unroll
    for (int c = 0; c < E / 8; ++c) {
      uint4 u = *(const uint4*)(src2 + base + c * 8);
      const unsigned short* us = (const unsigned short*)&u;
#pragma unroll
      for (int j = 0; j < 8; ++j) v[c * 8 + j] += bf2f(us[j]);
    }
  }
  if constexpr (BIAS) {
#pragma unroll
    for (int i = 0; i < E; ++i) v[i] += bias[tid * E + i];
  }
  if constexpr (SILU) {
#pragma unroll
    for (int i = 0; i < E; ++i) v[i] = v[i] / (1.f + __expf(-v[i]));
  }
  float s = 0.f, q = 0.f;
#pragma unroll
  for (int i = 0; i < E; ++i) {
    s += v[i];
    q += v[i] * v[i];
  }
#pragma unroll
  for (int m = 1; m < 64; m <<= 1) {
    s += __shfl_xor(s, m);
    q += __shfl_xor(q, m);
  }
  __shared__ float rs[4], rq[4];
  if ((tid & 63) == 0) {
    rs[tid >> 6] = s;
    rq[tid >> 6] = q;
  }
  __syncthreads();
  s = rs[0] + rs[1] + rs[2] + rs[3];
  q = rq[0] + rq[1] + rq[2] + rq[3];
  const float mean = s / NC;
  const float rstd = rsqrtf(q / NC - mean * mean + 1e-5f);
#pragma unroll
  for (int i = 0; i < E; ++i)
    v[i] = (v[i] - mean) * rstd * gamma[tid * E + i] + beta[tid * E + i];
  if constexpr (OUTF32) {
#pragma unroll
    for (int c = 0; c < E / 4; ++c) {
      float4 f = {v[c * 4], v[c * 4 + 1], v[c * 4 + 2], v[c * 4 + 3]};
      *(float4*)(dstf + base + c * 4) = f;
    }
  } else {
#pragma unroll
    for (int c = 0; c < E / 8; ++c) {
      uint4 u;
      unsigned* up = (unsigned*)&u;
#pragma unroll
      for (int j = 0; j < 4; ++j)
        up[j] = (unsigned)f2bf(v[c * 8 + j * 2]) | ((unsigned)f2bf(v[c * 8 + j * 2 + 1]) << 16);
      *(uint4*)(dstb + base + c * 8) = u;
    }
  }
}

// ---------------------------------------------------------------------------
extern "C" void kernel_launch(void* const* d_in, const int* in_sizes, int n_in,
                              void* d_out, int out_size, void* d_ws, size_t ws_size,
                              hipStream_t stream) {
  (void)in_sizes; (void)n_in; (void)out_size; (void)ws_size;
  const float* x     = (const float*)d_in[0];
  const float* wq    = (const float*)d_in[1];
  const float* wk    = (const float*)d_in[2];
  const float* wv    = (const float*)d_in[3];
  const float* wo    = (const float*)d_in[4];
  const float* ln1_g = (const float*)d_in[5];
  const float* ln1_b = (const float*)d_in[6];
  const float* w1    = (const float*)d_in[7];
  const float* b1    = (const float*)d_in[8];
  const float* lnf_g = (const float*)d_in[9];
  const float* lnf_b = (const float*)d_in[10];
  const float* w2    = (const float*)d_in[11];
  const float* b2    = (const float*)d_in[12];

  unsigned short* ws = (unsigned short*)d_ws;
  unsigned short* wqkvT  = ws;                                  // [3072][2048]
  unsigned short* woT    = wqkvT  + (size_t)3072 * 2048;        // [2048][2048]
  unsigned short* w1T    = woT    + (size_t)2048 * 2048;        // [8192][2048]
  unsigned short* w2T    = w1T    + (size_t)8192 * 2048;        // [2048][8192]
  unsigned short* xb     = w2T    + (size_t)2048 * 8192;        // x bf16 -> h -> FFN2 partial0
  unsigned short* qkv    = xb     + (size_t)4096 * 2048;        // qkv -> O-proj partial0
  unsigned short* vt     = qkv    + (size_t)4096 * 3072;        // [8][128][2048]
  unsigned short* attn_o = vt     + (size_t)4096 * 512;         // attn out -> FFN2 partial1
  unsigned short* f1     = attn_o + (size_t)4096 * 2048;        // O-proj partial1 -> FFN1 out

  (void)hipFuncSetAttribute((const void*)gemm8ph<1>,
                            hipFuncAttributeMaxDynamicSharedMemorySize, 131072);
  (void)hipFuncSetAttribute((const void*)gemm8ph<2>,
                            hipFuncAttributeMaxDynamicSharedMemorySize, 131072);
  (void)hipFuncSetAttribute((const void*)attn_kernel,
                            hipFuncAttributeMaxDynamicSharedMemorySize, 65536);

  const dim3 tb(32, 8);
  cast_f32_bf16<<<8192, 256, 0, stream>>>(x, xb, 4096 * 2048);
  transcast<<<dim3(64, 64),  tb, 0, stream>>>(wq, wqkvT, 2048, 2048, 2048, 0);
  transcast<<<dim3(16, 64),  tb, 0, stream>>>(wk, wqkvT, 2048, 512, 2048, 2048);
  transcast<<<dim3(16, 64),  tb, 0, stream>>>(wv, wqkvT, 2048, 512, 2048, 2560);
  transcast<<<dim3(64, 64),  tb, 0, stream>>>(wo, woT, 2048, 2048, 2048, 0);
  transcast<<<dim3(256, 64), tb, 0, stream>>>(w1, w1T, 2048, 8192, 2048, 0);
  transcast<<<dim3(64, 256), tb, 0, stream>>>(w2, w2T, 8192, 2048, 8192, 0);

  // QKV: M=4096 N=3072 K=2048 (KS=1)
  gemm8ph<1><<<dim3(12, 16, 1), 512, 131072, stream>>>(xb, wqkvT, qkv, nullptr, 3072, 2048);
  l2norm_qk<<<20480, 256, 0, stream>>>(qkv);
  vtrans<<<8192, 256, 0, stream>>>(qkv, vt);
  attn_kernel<<<256, 512, 65536, stream>>>(qkv, vt, attn_o);
  // O-proj: M=4096 N=2048 K=2048, split-K=2
  gemm8ph<2><<<dim3(8, 16, 2), 512, 131072, stream>>>(attn_o, woT, qkv, f1, 2048, 1024);
  ln_row<2048, false, false, false, true><<<4096, 256, 0, stream>>>(
      qkv, f1, xb, nullptr, ln1_g, ln1_b, nullptr);
  // FFN1: M=4096 N=8192 K=2048 (KS=1)
  gemm8ph<1><<<dim3(32, 16, 1), 512, 131072, stream>>>(xb, w1T, f1, nullptr, 8192, 2048);
  ln_row<8192, true, true, false, false><<<4096, 256, 0, stream>>>(
      f1, nullptr, f1, nullptr, lnf_g, lnf_b, b1);
  // FFN2: M=4096 N=2048 K=8192, split-K=2
  gemm8ph<2><<<dim3(8, 16, 2), 512, 131072, stream>>>(f1, w2T, xb, attn_o, 2048, 4096);
  ln_row<2048, true, false, true, true><<<4096, 256, 0, stream>>>(
      xb, attn_o, nullptr, (float*)d_out, ln1_g, ln1_b, b2);
}